// Round 2
// baseline (286.155 us; speedup 1.0000x reference)
//
#include <hip/hip_runtime.h>
#include <stdint.h>

typedef __bf16 bf16_t;
typedef __attribute__((ext_vector_type(8))) __bf16 bf16x8;
typedef __attribute__((ext_vector_type(4))) float f32x4;

#define NDIM 4096

// ---------------------------------------------------------------------------
// BFP quantize: groups of 64 share exponent of group max; 4 floats/thread ->
// 16-lane butterfly max. Grid-stride (2048 blocks) instead of 32768 one-shot
// blocks to probe dispatch-side pathology. grid.y selects tensor.
// ---------------------------------------------------------------------------
__global__ __launch_bounds__(256) void quant_bfp(const float* __restrict__ in0,
                                                 bf16_t* __restrict__ out0,
                                                 const float* __restrict__ in1,
                                                 bf16_t* __restrict__ out1) {
    const float* in = blockIdx.y ? in1 : in0;
    bf16_t* out     = blockIdx.y ? out1 : out0;
    const int stride = gridDim.x * 256;
    for (int t = blockIdx.x * 256 + threadIdx.x; t < NDIM * NDIM / 4; t += stride) {
        float4 v = ((const float4*)in)[t];
        float m = fmaxf(fmaxf(fabsf(v.x), fabsf(v.y)), fmaxf(fabsf(v.z), fabsf(v.w)));
        m = fmaxf(m, __shfl_xor(m, 1));
        m = fmaxf(m, __shfl_xor(m, 2));
        m = fmaxf(m, __shfl_xor(m, 4));
        m = fmaxf(m, __shfl_xor(m, 8));
        const int e = (int)((__float_as_uint(m) >> 23) & 0xFF) - 127;
        float step = __uint_as_float((uint32_t)(e + 120) << 23);  // 2^(e-7)
        float inv  = __uint_as_float((uint32_t)(134 - e) << 23);  // 2^(7-e)
        if (m == 0.0f) { step = 0.0f; inv = 0.0f; }
        float q0 = fminf(fmaxf(rintf(v.x * inv), -128.0f), 127.0f) * step;
        float q1 = fminf(fmaxf(rintf(v.y * inv), -128.0f), 127.0f) * step;
        float q2 = fminf(fmaxf(rintf(v.z * inv), -128.0f), 127.0f) * step;
        float q3 = fminf(fmaxf(rintf(v.w * inv), -128.0f), 127.0f) * step;
        union { bf16_t b[4]; uint2 u; } o;
        o.b[0] = (bf16_t)q0; o.b[1] = (bf16_t)q1;
        o.b[2] = (bf16_t)q2; o.b[3] = (bf16_t)q3;
        ((uint2*)out)[t] = o.u;
    }
}

// ---------------------------------------------------------------------------
// GEMM, 256x256-tile 8-phase schedule (m201 template). Round-2 changes:
//  * sched_barrier(0) on both sides of every s_barrier: pins MFMA clusters
//    inside their phase (register-only MFMA otherwise drifts across the
//    memory-clobber fences — rule #18 class).
//  * vmcnt(4) at ph4/ph8 ONLY (was 8/6/8/6 at ph2/4/6/8). Queue-traced:
//    both A-halves of a buffer are read from ph1 (wr=0 reads h0, wr=1 reads
//    h1), so the old WAITV(6)@ph8 left A-h1 unguarded (latent race) while
//    WAITV(8)@ph2/6 guarded nothing. With N=4 at ph4/ph8 every half-tile is
//    provably complete before first read, and the loop has 2 waits not 4.
//  * lgkmcnt(8) pre-barrier hint on the 12-ds_read phases (template option).
// ---------------------------------------------------------------------------
__device__ __forceinline__ void g2l16(const bf16_t* g, void* l) {
    __builtin_amdgcn_global_load_lds(
        (__attribute__((address_space(1))) void*)g,
        (__attribute__((address_space(3))) void*)l, 16, 0, 0);
}

#define FENCE() asm volatile("" ::: "memory")
#define BAR()   do { FENCE(); __builtin_amdgcn_sched_barrier(0);              \
                     __builtin_amdgcn_s_barrier();                            \
                     __builtin_amdgcn_sched_barrier(0); FENCE(); } while (0)
#define WAITV(n) asm volatile("s_waitcnt vmcnt(" #n ")" ::: "memory")
#define LGKM8()  asm volatile("s_waitcnt lgkmcnt(8)" ::: "memory")

// stage one 128x64 half-tile (2 x global_load_lds dwordx4 per thread)
#define STAGE_A(b, h, ko) do {                                                  \
    g2l16(gA + (size_t)((h) * 128) * NDIM + (ko),                               \
          (char*)sA + (b) * 32768 + (h) * 16384 + tid * 16);                    \
    g2l16(gA + (size_t)((h) * 128 + 64) * NDIM + (ko),                          \
          (char*)sA + (b) * 32768 + (h) * 16384 + 8192 + tid * 16);             \
} while (0)
#define STAGE_B(b, h, ko) do {                                                  \
    g2l16(gB + (size_t)((h) * 128) * NDIM + (ko),                               \
          (char*)sB + (b) * 32768 + (h) * 16384 + tid * 16);                    \
    g2l16(gB + (size_t)((h) * 128 + 64) * NDIM + (ko),                          \
          (char*)sB + (b) * 32768 + (h) * 16384 + 8192 + tid * 16);             \
} while (0)

// register-fragment loads (swizzled read side, 0 bank conflicts measured)
#define LDA(b, qm) do {                                                         \
    _Pragma("unroll")                                                           \
    for (int i_ = 0; i_ < 4; ++i_) {                                            \
        const int r_ = (b) * 16384 + aRow + ((qm) * 64 + i_ * 16) * 64;         \
        afr[i_][0] = *(const bf16x8*)&sA[r_ + ce0];                             \
        afr[i_][1] = *(const bf16x8*)&sA[r_ + ce1];                             \
    }                                                                           \
} while (0)
#define LDB(b, qn) do {                                                         \
    _Pragma("unroll")                                                           \
    for (int j_ = 0; j_ < 2; ++j_) {                                            \
        const int r_ = (b) * 16384 + bRow + ((qn) * 32 + j_ * 16) * 64;         \
        bfr[qn][j_][0] = *(const bf16x8*)&sB[r_ + ce0];                         \
        bfr[qn][j_][1] = *(const bf16x8*)&sB[r_ + ce1];                         \
    }                                                                           \
} while (0)

// one C-quadrant x K=64: 16 MFMA, prio-boosted
#define MFMAQ(qm, qn) do {                                                      \
    __builtin_amdgcn_s_setprio(1);                                              \
    _Pragma("unroll")                                                           \
    for (int i_ = 0; i_ < 4; ++i_)                                              \
        _Pragma("unroll")                                                       \
        for (int j_ = 0; j_ < 2; ++j_) {                                        \
            acc[(qm)*4+i_][(qn)*2+j_] = __builtin_amdgcn_mfma_f32_16x16x32_bf16(\
                afr[i_][0], bfr[qn][j_][0], acc[(qm)*4+i_][(qn)*2+j_], 0, 0, 0);\
            acc[(qm)*4+i_][(qn)*2+j_] = __builtin_amdgcn_mfma_f32_16x16x32_bf16(\
                afr[i_][1], bfr[qn][j_][1], acc[(qm)*4+i_][(qn)*2+j_], 0, 0, 0);\
        }                                                                       \
    __builtin_amdgcn_s_setprio(0);                                              \
} while (0)

__global__ __launch_bounds__(512, 2) void gemm_bfp(const bf16_t* __restrict__ A,
                                                   const bf16_t* __restrict__ B,
                                                   const float* __restrict__ bias,
                                                   float* __restrict__ C) {
    __shared__ bf16_t sA[2 * 256 * 64];   // 64 KiB  [buf][row 0..255][k 0..63]
    __shared__ bf16_t sB[2 * 256 * 64];   // 64 KiB

    const int tid  = threadIdx.x;
    const int wave = tid >> 6;
    const int lane = tid & 63;
    const int wr   = wave >> 2;           // 0..1  (M)
    const int wc   = wave & 3;            // 0..3  (N)

    // XCD-chunked remap: XCD x owns wg [32x, 32x+32) = 2 bm rows, all bn
    const int p  = blockIdx.x;
    const int wg = (p & 7) * 32 + (p >> 3);
    const int bm = wg >> 4;
    const int bn = wg & 15;

    // staging geometry: thread -> (row = tid>>3, chunk = tid&7), XOR-swizzled src
    const int srow = tid >> 3;
    const int swz  = ((tid & 7) ^ (srow & 7)) * 8;
    const bf16_t* gA = A + (size_t)(bm * 256 + srow) * NDIM + swz;
    const bf16_t* gB = B + (size_t)(bn * 256 + srow) * NDIM + swz;

    // read-side geometry (row == l16 mod 8 -> same swizzle key)
    const int quad = lane >> 4;
    const int l16  = lane & 15;
    const int rsw  = l16 & 7;
    const int ce0  = (quad ^ rsw) * 8;        // ks=0 chunk (elems)
    const int ce1  = ((4 + quad) ^ rsw) * 8;  // ks=32 chunk
    const int aRow = (wr * 128 + l16) * 64;   // elem base of wave's A rows
    const int bRow = (wc * 64 + l16) * 64;

    f32x4 acc[8][4];
#pragma unroll
    for (int i = 0; i < 8; ++i)
#pragma unroll
        for (int j = 0; j < 4; ++j) acc[i][j] = (f32x4){0.0f, 0.0f, 0.0f, 0.0f};

    bf16x8 afr[4][2];      // current qm half: 4 frags x 2 k-slices
    bf16x8 bfr[2][2][2];   // both qn halves live across the tile

    // prologue: tile0 A+B, tile1 B (tile1 A arrives from ph1/ph2 of tile0)
    STAGE_A(0, 0, 0); STAGE_A(0, 1, 0);
    STAGE_B(0, 0, 0); STAGE_B(0, 1, 0);
    STAGE_B(1, 0, 64); STAGE_B(1, 1, 64);
    WAITV(0);
    BAR();

    for (int kt = 0; kt < NDIM; kt += 128) {
        const int koA1 = kt + 64;                          // tile 2i+1 A (always in range)
        const int koN2 = (kt + 128 < NDIM) ? kt + 128 : 0; // tile 2i+2 A,B (dummy at tail)
        const int koB3 = (kt + 192 < NDIM) ? kt + 192 : 0; // tile 2i+3 B   (dummy at tail)

        // ---- tile 2i: compute buf0; A-stages -> buf1, B-stages -> buf0 ----
        LDA(0, 0); LDB(0, 0);            // ph1 (12 ds_reads)
        STAGE_A(1, 0, koA1);
        LGKM8();
        BAR();
        MFMAQ(0, 0);
        BAR();

        LDB(0, 1);                       // ph2
        STAGE_A(1, 1, koA1);
        BAR();
        MFMAQ(0, 1);
        BAR();

        LDA(0, 1);                       // ph3
        STAGE_B(0, 0, koN2);
        BAR();
        MFMAQ(1, 1);
        BAR();

        STAGE_B(0, 1, koN2);             // ph4
        BAR();
        MFMAQ(1, 0);
        WAITV(4);                        // completes A(1,*) [ph5 read] + prev B(1,*)
        BAR();

        // ---- tile 2i+1: compute buf1; A-stages -> buf0, B-stages -> buf1 ----
        LDA(1, 0); LDB(1, 0);            // ph5 (12 ds_reads)
        STAGE_A(0, 0, koN2);
        LGKM8();
        BAR();
        MFMAQ(0, 0);
        BAR();

        LDB(1, 1);                       // ph6
        STAGE_A(0, 1, koN2);
        BAR();
        MFMAQ(0, 1);
        BAR();

        LDA(1, 1);                       // ph7
        STAGE_B(1, 0, koB3);
        BAR();
        MFMAQ(1, 1);
        BAR();

        STAGE_B(1, 1, koB3);             // ph8
        BAR();
        MFMAQ(1, 0);
        WAITV(4);                        // completes A(0,*),B(0,*) [next ph1 reads]
        BAR();
    }

    // epilogue: C/D layout col = lane&15, row = quad*4 + reg  [m89-verified]
    const int row0 = bm * 256 + wr * 128 + quad * 4;
    const int col0 = bn * 256 + wc * 64 + l16;
#pragma unroll
    for (int nj = 0; nj < 4; ++nj) {
        const int c = col0 + nj * 16;
        const float bv = 2.0f * bias[c];
#pragma unroll
        for (int mi = 0; mi < 8; ++mi) {
            const int r = row0 + mi * 16;
#pragma unroll
            for (int reg = 0; reg < 4; ++reg)
                C[(size_t)(r + reg) * NDIM + c] = acc[mi][nj][reg] + bv;
        }
    }
}

extern "C" void kernel_launch(void* const* d_in, const int* in_sizes, int n_in,
                              void* d_out, int out_size, void* d_ws, size_t ws_size,
                              hipStream_t stream) {
    const float* x    = (const float*)d_in[0];
    const float* w    = (const float*)d_in[1];
    const float* bias = (const float*)d_in[2];
    float* out = (float*)d_out;

    bf16_t* xq = (bf16_t*)d_ws;                         // 32 MB
    bf16_t* wq = xq + (size_t)NDIM * NDIM;              // 32 MB

    dim3 qgrid(1024, 2);                                // grid-stride, 8 blk/CU
    quant_bfp<<<qgrid, 256, 0, stream>>>(x, xq, w, wq);

    dim3 grid(256);                                     // 16x16 tiles, 1 block/CU
    gemm_bfp<<<grid, 512, 0, stream>>>(xq, wq, bias, out);
}

// Round 3
// 285.913 us; speedup vs baseline: 1.0008x; 1.0008x over previous
//
#include <hip/hip_runtime.h>
#include <stdint.h>

typedef __bf16 bf16_t;
typedef __attribute__((ext_vector_type(8))) __bf16 bf16x8;
typedef __attribute__((ext_vector_type(4))) float f32x4;

#define NDIM 4096

// ---------------------------------------------------------------------------
// BFP quantize (unchanged from round 2)
// ---------------------------------------------------------------------------
__global__ __launch_bounds__(256) void quant_bfp(const float* __restrict__ in0,
                                                 bf16_t* __restrict__ out0,
                                                 const float* __restrict__ in1,
                                                 bf16_t* __restrict__ out1) {
    const float* in = blockIdx.y ? in1 : in0;
    bf16_t* out     = blockIdx.y ? out1 : out0;
    const int stride = gridDim.x * 256;
    for (int t = blockIdx.x * 256 + threadIdx.x; t < NDIM * NDIM / 4; t += stride) {
        float4 v = ((const float4*)in)[t];
        float m = fmaxf(fmaxf(fabsf(v.x), fabsf(v.y)), fmaxf(fabsf(v.z), fabsf(v.w)));
        m = fmaxf(m, __shfl_xor(m, 1));
        m = fmaxf(m, __shfl_xor(m, 2));
        m = fmaxf(m, __shfl_xor(m, 4));
        m = fmaxf(m, __shfl_xor(m, 8));
        const int e = (int)((__float_as_uint(m) >> 23) & 0xFF) - 127;
        float step = __uint_as_float((uint32_t)(e + 120) << 23);  // 2^(e-7)
        float inv  = __uint_as_float((uint32_t)(134 - e) << 23);  // 2^(7-e)
        if (m == 0.0f) { step = 0.0f; inv = 0.0f; }
        float q0 = fminf(fmaxf(rintf(v.x * inv), -128.0f), 127.0f) * step;
        float q1 = fminf(fmaxf(rintf(v.y * inv), -128.0f), 127.0f) * step;
        float q2 = fminf(fmaxf(rintf(v.z * inv), -128.0f), 127.0f) * step;
        float q3 = fminf(fmaxf(rintf(v.w * inv), -128.0f), 127.0f) * step;
        union { bf16_t b[4]; uint2 u; } o;
        o.b[0] = (bf16_t)q0; o.b[1] = (bf16_t)q1;
        o.b[2] = (bf16_t)q2; o.b[3] = (bf16_t)q3;
        ((uint2*)out)[t] = o.u;
    }
}

// ---------------------------------------------------------------------------
// GEMM, 256x256 8-phase schedule. Round-3 change: QUADRANT-LOCAL LDS regions.
//   A-region qm holds global rows [qm*64,qm*64+64) u [128+qm*64, +64)
//   B-region qn holds global rows {wc*64+qn*32+[0,32) : wc=0..3}
// Phase reads now touch exactly one region each: p1:{A-r0,B-r0} p2:{B-r1}
// p3:{A-r1} p4:{} -> regions die right after one phase -> each region is
// staged 6-7 phases before consumption and vmcnt(6) at p4/p8 is race-free
// (3 most recent regions in flight across the waits, m201's schedule).
// Swizzle keys preserved (region offsets = 0 mod 8 rows on both sides).
// ---------------------------------------------------------------------------
__device__ __forceinline__ void g2l16(const bf16_t* g, void* l) {
    __builtin_amdgcn_global_load_lds(
        (__attribute__((address_space(1))) void*)g,
        (__attribute__((address_space(3))) void*)l, 16, 0, 0);
}

#define FENCE() asm volatile("" ::: "memory")
#define BAR()   do { FENCE(); __builtin_amdgcn_sched_barrier(0);              \
                     __builtin_amdgcn_s_barrier();                            \
                     __builtin_amdgcn_sched_barrier(0); FENCE(); } while (0)
#define WAITV(n) asm volatile("s_waitcnt vmcnt(" #n ")" ::: "memory")
#define LGKM8()  asm volatile("s_waitcnt lgkmcnt(8)" ::: "memory")

// stage A-region r of buf b: slots [0,64)=rows r*64+srow, [64,128)=+128
#define STAGE_A(b, r, ko) do {                                                  \
    g2l16(gA + (size_t)((r) * 64) * NDIM + (ko),                                \
          (char*)sA + (b) * 32768 + (r) * 16384 + tid * 16);                    \
    g2l16(gA + (size_t)((r) * 64 + 128) * NDIM + (ko),                          \
          (char*)sA + (b) * 32768 + (r) * 16384 + 8192 + tid * 16);             \
} while (0)
// stage B-region r: gB pre-maps srow -> (srow>>5)*64+(srow&31); +r*32, +128
#define STAGE_B(b, r, ko) do {                                                  \
    g2l16(gB + (size_t)((r) * 32) * NDIM + (ko),                                \
          (char*)sB + (b) * 32768 + (r) * 16384 + tid * 16);                    \
    g2l16(gB + (size_t)((r) * 32 + 128) * NDIM + (ko),                          \
          (char*)sB + (b) * 32768 + (r) * 16384 + 8192 + tid * 16);             \
} while (0)

// fragment loads: region-local slots (A: wr*64+i*16+l16, B: wc*32+j*16+l16)
#define LDA(b, qm) do {                                                         \
    _Pragma("unroll")                                                           \
    for (int i_ = 0; i_ < 4; ++i_) {                                            \
        const int r_ = (b) * 16384 + (qm) * 8192 + aRow + i_ * 1024;            \
        afr[i_][0] = *(const bf16x8*)&sA[r_ + ce0];                             \
        afr[i_][1] = *(const bf16x8*)&sA[r_ + ce1];                             \
    }                                                                           \
} while (0)
#define LDB(b, qn) do {                                                         \
    _Pragma("unroll")                                                           \
    for (int j_ = 0; j_ < 2; ++j_) {                                            \
        const int r_ = (b) * 16384 + (qn) * 8192 + bRow + j_ * 1024;            \
        bfr[qn][j_][0] = *(const bf16x8*)&sB[r_ + ce0];                         \
        bfr[qn][j_][1] = *(const bf16x8*)&sB[r_ + ce1];                         \
    }                                                                           \
} while (0)

// one C-quadrant x K=64: 16 MFMA, prio-boosted
#define MFMAQ(qm, qn) do {                                                      \
    __builtin_amdgcn_s_setprio(1);                                              \
    _Pragma("unroll")                                                           \
    for (int i_ = 0; i_ < 4; ++i_)                                              \
        _Pragma("unroll")                                                       \
        for (int j_ = 0; j_ < 2; ++j_) {                                        \
            acc[(qm)*4+i_][(qn)*2+j_] = __builtin_amdgcn_mfma_f32_16x16x32_bf16(\
                afr[i_][0], bfr[qn][j_][0], acc[(qm)*4+i_][(qn)*2+j_], 0, 0, 0);\
            acc[(qm)*4+i_][(qn)*2+j_] = __builtin_amdgcn_mfma_f32_16x16x32_bf16(\
                afr[i_][1], bfr[qn][j_][1], acc[(qm)*4+i_][(qn)*2+j_], 0, 0, 0);\
        }                                                                       \
    __builtin_amdgcn_s_setprio(0);                                              \
} while (0)

__global__ __launch_bounds__(512, 2) void gemm_bfp(const bf16_t* __restrict__ A,
                                                   const bf16_t* __restrict__ B,
                                                   const float* __restrict__ bias,
                                                   float* __restrict__ C) {
    __shared__ bf16_t sA[2 * 256 * 64];   // [buf][region][slot 0..127][k 0..63]
    __shared__ bf16_t sB[2 * 256 * 64];

    const int tid  = threadIdx.x;
    const int wave = tid >> 6;
    const int lane = tid & 63;
    const int wr   = wave >> 2;           // 0..1  (M)
    const int wc   = wave & 3;            // 0..3  (N)

    const int p  = blockIdx.x;
    const int wg = (p & 7) * 32 + (p >> 3);
    const int bm = wg >> 4;
    const int bn = wg & 15;

    // staging geometry: thread -> (srow = tid>>3, chunk = tid&7), XOR-swz src
    const int srow = tid >> 3;
    const int swz  = ((tid & 7) ^ (srow & 7)) * 8;
    const bf16_t* gA = A + (size_t)(bm * 256 + srow) * NDIM + swz;
    const bf16_t* gB = B + (size_t)(bn * 256 + (srow >> 5) * 64 + (srow & 31)) * NDIM + swz;

    // read-side geometry (slot & 7 == l16 & 7 -> same swizzle key as source)
    const int quad = lane >> 4;
    const int l16  = lane & 15;
    const int rsw  = l16 & 7;
    const int ce0  = (quad ^ rsw) * 8;        // global k-chunk quad   (ks=0)
    const int ce1  = ((4 + quad) ^ rsw) * 8;  // global k-chunk 4+quad (ks=32)
    const int aRow = (wr * 64 + l16) * 64;    // region-local slot base (elems)
    const int bRow = (wc * 32 + l16) * 64;

    f32x4 acc[8][4];
#pragma unroll
    for (int i = 0; i < 8; ++i)
#pragma unroll
        for (int j = 0; j < 4; ++j) acc[i][j] = (f32x4){0.0f, 0.0f, 0.0f, 0.0f};

    bf16x8 afr[4][2];
    bf16x8 bfr[2][2][2];

    // prologue: 7 regions. First 4 (tile0) drained by vmcnt(6); last 3 (tile1)
    // stay in flight and complete at iter-0's p4 wait, before p5-p7 reads.
    STAGE_A(0, 0, 0); STAGE_B(0, 0, 0); STAGE_B(0, 1, 0); STAGE_A(0, 1, 0);
    STAGE_A(1, 0, 64); STAGE_B(1, 0, 64); STAGE_B(1, 1, 64);
    WAITV(6);
    BAR();

    for (int kt = 0; kt < NDIM; kt += 128) {
        const int koA1 = kt + 64;                          // A(1,r1): this iter p7
        const int koN2 = (kt + 128 < NDIM) ? kt + 128 : 0; // buf0 regions, next iter
        const int koB3 = (kt + 192 < NDIM) ? kt + 192 : 0; // buf1 regions, next iter

        // p1: reads A(0,r0)+B(0,r0); stages A(1,r1) [dead since prev p7]
        LDA(0, 0); LDB(0, 0);
        STAGE_A(1, 1, koA1);
        LGKM8();
        BAR();
        MFMAQ(0, 0);
        BAR();

        // p2: reads B(0,r1); stages A(0,r0) [died p1]
        LDB(0, 1);
        STAGE_A(0, 0, koN2);
        BAR();
        MFMAQ(0, 1);
        BAR();

        // p3: reads A(0,r1); stages B(0,r0) [died p1]
        LDA(0, 1);
        STAGE_B(0, 0, koN2);
        BAR();
        MFMAQ(1, 1);
        BAR();

        // p4: stages B(0,r1) [died p2]; wait drains prev p6,p7,p8 + p1
        STAGE_B(0, 1, koN2);
        BAR();
        MFMAQ(1, 0);
        WAITV(6);
        BAR();

        // p5: reads A(1,r0)+B(1,r0); stages A(0,r1) [died p3]
        LDA(1, 0); LDB(1, 0);
        STAGE_A(0, 1, koN2);
        LGKM8();
        BAR();
        MFMAQ(0, 0);
        BAR();

        // p6: reads B(1,r1); stages A(1,r0) [died p5]
        LDB(1, 1);
        STAGE_A(1, 0, koB3);
        BAR();
        MFMAQ(0, 1);
        BAR();

        // p7: reads A(1,r1); stages B(1,r0) [died p5]
        LDA(1, 1);
        STAGE_B(1, 0, koB3);
        BAR();
        MFMAQ(1, 1);
        BAR();

        // p8: stages B(1,r1) [died p6]; wait drains p2,p3,p4,p5
        STAGE_B(1, 1, koB3);
        BAR();
        MFMAQ(1, 0);
        WAITV(6);
        BAR();
    }

    // epilogue (unchanged; fragment->C mapping independent of LDS layout)
    const int row0 = bm * 256 + wr * 128 + quad * 4;
    const int col0 = bn * 256 + wc * 64 + l16;
#pragma unroll
    for (int nj = 0; nj < 4; ++nj) {
        const int c = col0 + nj * 16;
        const float bv = 2.0f * bias[c];
#pragma unroll
        for (int mi = 0; mi < 8; ++mi) {
            const int r = row0 + mi * 16;
#pragma unroll
            for (int reg = 0; reg < 4; ++reg)
                __builtin_nontemporal_store(acc[mi][nj][reg] + bv,
                                            &C[(size_t)(r + reg) * NDIM + c]);
        }
    }
}

extern "C" void kernel_launch(void* const* d_in, const int* in_sizes, int n_in,
                              void* d_out, int out_size, void* d_ws, size_t ws_size,
                              hipStream_t stream) {
    const float* x    = (const float*)d_in[0];
    const float* w    = (const float*)d_in[1];
    const float* bias = (const float*)d_in[2];
    float* out = (float*)d_out;

    bf16_t* xq = (bf16_t*)d_ws;                         // 32 MB
    bf16_t* wq = xq + (size_t)NDIM * NDIM;              // 32 MB

    dim3 qgrid(1024, 2);
    quant_bfp<<<qgrid, 256, 0, stream>>>(x, xq, w, wq);

    dim3 grid(256);
    gemm_bfp<<<grid, 512, 0, stream>>>(xq, wq, bias, out);
}

// Round 4
// 284.415 us; speedup vs baseline: 1.0061x; 1.0053x over previous
//
#include <hip/hip_runtime.h>
#include <stdint.h>

typedef __bf16 bf16_t;
typedef __attribute__((ext_vector_type(8))) __bf16 bf16x8;
typedef __attribute__((ext_vector_type(4))) float f32x4;

#define NDIM 4096

// ---------------------------------------------------------------------------
// BFP quantize (unchanged)
// ---------------------------------------------------------------------------
__global__ __launch_bounds__(256) void quant_bfp(const float* __restrict__ in0,
                                                 bf16_t* __restrict__ out0,
                                                 const float* __restrict__ in1,
                                                 bf16_t* __restrict__ out1) {
    const float* in = blockIdx.y ? in1 : in0;
    bf16_t* out     = blockIdx.y ? out1 : out0;
    const int stride = gridDim.x * 256;
    for (int t = blockIdx.x * 256 + threadIdx.x; t < NDIM * NDIM / 4; t += stride) {
        float4 v = ((const float4*)in)[t];
        float m = fmaxf(fmaxf(fabsf(v.x), fabsf(v.y)), fmaxf(fabsf(v.z), fabsf(v.w)));
        m = fmaxf(m, __shfl_xor(m, 1));
        m = fmaxf(m, __shfl_xor(m, 2));
        m = fmaxf(m, __shfl_xor(m, 4));
        m = fmaxf(m, __shfl_xor(m, 8));
        const int e = (int)((__float_as_uint(m) >> 23) & 0xFF) - 127;
        float step = __uint_as_float((uint32_t)(e + 120) << 23);  // 2^(e-7)
        float inv  = __uint_as_float((uint32_t)(134 - e) << 23);  // 2^(7-e)
        if (m == 0.0f) { step = 0.0f; inv = 0.0f; }
        float q0 = fminf(fmaxf(rintf(v.x * inv), -128.0f), 127.0f) * step;
        float q1 = fminf(fmaxf(rintf(v.y * inv), -128.0f), 127.0f) * step;
        float q2 = fminf(fmaxf(rintf(v.z * inv), -128.0f), 127.0f) * step;
        float q3 = fminf(fmaxf(rintf(v.w * inv), -128.0f), 127.0f) * step;
        union { bf16_t b[4]; uint2 u; } o;
        o.b[0] = (bf16_t)q0; o.b[1] = (bf16_t)q1;
        o.b[2] = (bf16_t)q2; o.b[3] = (bf16_t)q3;
        ((uint2*)out)[t] = o.u;
    }
}

// ---------------------------------------------------------------------------
// GEMM, 256x256 tile, quadrant-local LDS regions (round-3 layout, proven
// correct). Round-4 change: ONE barrier per phase (8/iter, was 16).
// Phase = [BAR; reads(p); stage(s_p); MFMA(p); (vmcnt @p4,p8)].
// Rationale: MFMA floor is ~4715 cyc/iter; we spend 10275. With 2 barriers
// per phase all 8 waves ds_read in a no-compute window then all stall on
// lgkm together -> LDS and MFMA pipes alternate chip-wide. One barrier per
// phase lets waves skew within the span so reads of one wave overlap MFMA
// of another.
// Hazard proof (stages p1:A11 p2:A00 p3:B00 p4:B01 p5:A01 p6:A10 p7:B10
// p8:B11; reads p1:{A00,B00} p2:B01 p3:A01 p5:{A10,B10} p6:B11 p7:A11):
//  WAR: every region has >=1 barrier between last-read phase and stage-issue
//   phase (A00 p1->p2, A10 p5->p6 are the tight ones: 1 barrier each; VMEM
//   writes cannot land before issue, so issue-after-barrier suffices).
//  RAW: FIFO trace with vmcnt(6) at end of p4/p8: at p4-wait queue =
//   [A10',B10',B11',A11,A00,B00,B01] (14) -> drains 8 -> completes
//   A10',B10',B11',A11 before p5-p7 reads; at p8-wait completes
//   A00,B00,B01,A01 before p8..p3' reads. All regions complete >=0 phases
//   before first read. Same invariant as round-3 (absmax 0.0).
// ---------------------------------------------------------------------------
__device__ __forceinline__ void g2l16(const bf16_t* g, void* l) {
    __builtin_amdgcn_global_load_lds(
        (__attribute__((address_space(1))) void*)g,
        (__attribute__((address_space(3))) void*)l, 16, 0, 0);
}

#define FENCE() asm volatile("" ::: "memory")
#define BAR()   do { FENCE(); __builtin_amdgcn_sched_barrier(0);              \
                     __builtin_amdgcn_s_barrier();                            \
                     __builtin_amdgcn_sched_barrier(0); FENCE(); } while (0)
#define WAITV(n) asm volatile("s_waitcnt vmcnt(" #n ")" ::: "memory")

// stage A-region r of buf b: slots [0,64)=rows r*64+srow, [64,128)=+128
#define STAGE_A(b, r, ko) do {                                                  \
    g2l16(gA + (size_t)((r) * 64) * NDIM + (ko),                                \
          (char*)sA + (b) * 32768 + (r) * 16384 + tid * 16);                    \
    g2l16(gA + (size_t)((r) * 64 + 128) * NDIM + (ko),                          \
          (char*)sA + (b) * 32768 + (r) * 16384 + 8192 + tid * 16);             \
} while (0)
// stage B-region r: gB pre-maps srow -> (srow>>5)*64+(srow&31); +r*32, +128
#define STAGE_B(b, r, ko) do {                                                  \
    g2l16(gB + (size_t)((r) * 32) * NDIM + (ko),                                \
          (char*)sB + (b) * 32768 + (r) * 16384 + tid * 16);                    \
    g2l16(gB + (size_t)((r) * 32 + 128) * NDIM + (ko),                          \
          (char*)sB + (b) * 32768 + (r) * 16384 + 8192 + tid * 16);             \
} while (0)

// fragment loads: region-local slots (A: wr*64+i*16+l16, B: wc*32+j*16+l16)
#define LDA(b, qm) do {                                                         \
    _Pragma("unroll")                                                           \
    for (int i_ = 0; i_ < 4; ++i_) {                                            \
        const int r_ = (b) * 16384 + (qm) * 8192 + aRow + i_ * 1024;            \
        afr[i_][0] = *(const bf16x8*)&sA[r_ + ce0];                             \
        afr[i_][1] = *(const bf16x8*)&sA[r_ + ce1];                             \
    }                                                                           \
} while (0)
#define LDB(b, qn) do {                                                         \
    _Pragma("unroll")                                                           \
    for (int j_ = 0; j_ < 2; ++j_) {                                            \
        const int r_ = (b) * 16384 + (qn) * 8192 + bRow + j_ * 1024;            \
        bfr[qn][j_][0] = *(const bf16x8*)&sB[r_ + ce0];                         \
        bfr[qn][j_][1] = *(const bf16x8*)&sB[r_ + ce1];                         \
    }                                                                           \
} while (0)

// one C-quadrant x K=64: 16 MFMA, prio-boosted
#define MFMAQ(qm, qn) do {                                                      \
    __builtin_amdgcn_s_setprio(1);                                              \
    _Pragma("unroll")                                                           \
    for (int i_ = 0; i_ < 4; ++i_)                                              \
        _Pragma("unroll")                                                       \
        for (int j_ = 0; j_ < 2; ++j_) {                                        \
            acc[(qm)*4+i_][(qn)*2+j_] = __builtin_amdgcn_mfma_f32_16x16x32_bf16(\
                afr[i_][0], bfr[qn][j_][0], acc[(qm)*4+i_][(qn)*2+j_], 0, 0, 0);\
            acc[(qm)*4+i_][(qn)*2+j_] = __builtin_amdgcn_mfma_f32_16x16x32_bf16(\
                afr[i_][1], bfr[qn][j_][1], acc[(qm)*4+i_][(qn)*2+j_], 0, 0, 0);\
        }                                                                       \
    __builtin_amdgcn_s_setprio(0);                                              \
} while (0)

__global__ __launch_bounds__(512, 2) void gemm_bfp(const bf16_t* __restrict__ A,
                                                   const bf16_t* __restrict__ B,
                                                   const float* __restrict__ bias,
                                                   float* __restrict__ C) {
    __shared__ bf16_t sA[2 * 256 * 64];   // [buf][region][slot 0..127][k 0..63]
    __shared__ bf16_t sB[2 * 256 * 64];

    const int tid  = threadIdx.x;
    const int wave = tid >> 6;
    const int lane = tid & 63;
    const int wr   = wave >> 2;           // 0..1  (M)
    const int wc   = wave & 3;            // 0..3  (N)

    const int p  = blockIdx.x;
    const int wg = (p & 7) * 32 + (p >> 3);
    const int bm = wg >> 4;
    const int bn = wg & 15;

    // staging geometry: thread -> (srow = tid>>3, chunk = tid&7), XOR-swz src
    const int srow = tid >> 3;
    const int swz  = ((tid & 7) ^ (srow & 7)) * 8;
    const bf16_t* gA = A + (size_t)(bm * 256 + srow) * NDIM + swz;
    const bf16_t* gB = B + (size_t)(bn * 256 + (srow >> 5) * 64 + (srow & 31)) * NDIM + swz;

    // read-side geometry (slot & 7 == l16 & 7 -> same swizzle key as source)
    const int quad = lane >> 4;
    const int l16  = lane & 15;
    const int rsw  = l16 & 7;
    const int ce0  = (quad ^ rsw) * 8;        // global k-chunk quad   (ks=0)
    const int ce1  = ((4 + quad) ^ rsw) * 8;  // global k-chunk 4+quad (ks=32)
    const int aRow = (wr * 64 + l16) * 64;    // region-local slot base (elems)
    const int bRow = (wc * 32 + l16) * 64;

    f32x4 acc[8][4];
#pragma unroll
    for (int i = 0; i < 8; ++i)
#pragma unroll
        for (int j = 0; j < 4; ++j) acc[i][j] = (f32x4){0.0f, 0.0f, 0.0f, 0.0f};

    bf16x8 afr[4][2];
    bf16x8 bfr[2][2][2];

    // prologue: 7 regions; vmcnt(6) completes the 4 tile-0 regions (A00,B00,
    // B01,A01); the 3 tile-1 regions stay in flight, completed at iter-0 p4.
    STAGE_A(0, 0, 0); STAGE_B(0, 0, 0); STAGE_B(0, 1, 0); STAGE_A(0, 1, 0);
    STAGE_A(1, 0, 64); STAGE_B(1, 0, 64); STAGE_B(1, 1, 64);
    WAITV(6);

    for (int kt = 0; kt < NDIM; kt += 128) {
        const int koA1 = kt + 64;                          // A(1,r1): this iter p7 read
        const int koN2 = (kt + 128 < NDIM) ? kt + 128 : 0; // buf0 regions, next iter
        const int koB3 = (kt + 192 < NDIM) ? kt + 192 : 0; // buf1 regions, next iter

        // p1: reads A(0,r0)+B(0,r0); stages A(1,r1) [dead since prev p7]
        BAR();
        LDA(0, 0); LDB(0, 0);
        STAGE_A(1, 1, koA1);
        MFMAQ(0, 0);

        // p2: reads B(0,r1); stages A(0,r0) [read p1, 1 barrier back]
        BAR();
        LDB(0, 1);
        STAGE_A(0, 0, koN2);
        MFMAQ(0, 1);

        // p3: reads A(0,r1); stages B(0,r0) [read p1]
        BAR();
        LDA(0, 1);
        STAGE_B(0, 0, koN2);
        MFMAQ(1, 1);

        // p4: stages B(0,r1) [read p2]; vmcnt completes A10',B10',B11',A11
        BAR();
        STAGE_B(0, 1, koN2);
        MFMAQ(1, 0);
        WAITV(6);

        // p5: reads A(1,r0)+B(1,r0); stages A(0,r1) [read p3]
        BAR();
        LDA(1, 0); LDB(1, 0);
        STAGE_A(0, 1, koN2);
        MFMAQ(0, 0);

        // p6: reads B(1,r1); stages A(1,r0) [read p5]
        BAR();
        LDB(1, 1);
        STAGE_A(1, 0, koB3);
        MFMAQ(0, 1);

        // p7: reads A(1,r1); stages B(1,r0) [read p5]
        BAR();
        LDA(1, 1);
        STAGE_B(1, 0, koB3);
        MFMAQ(1, 1);

        // p8: stages B(1,r1) [read p6]; vmcnt completes A00,B00,B01,A01
        BAR();
        STAGE_B(1, 1, koB3);
        MFMAQ(1, 0);
        WAITV(6);
    }

    // epilogue (plain stores; NT variant measured +3 us WRITE_SIZE, reverted)
    const int row0 = bm * 256 + wr * 128 + quad * 4;
    const int col0 = bn * 256 + wc * 64 + l16;
#pragma unroll
    for (int nj = 0; nj < 4; ++nj) {
        const int c = col0 + nj * 16;
        const float bv = 2.0f * bias[c];
#pragma unroll
        for (int mi = 0; mi < 8; ++mi) {
            const int r = row0 + mi * 16;
#pragma unroll
            for (int reg = 0; reg < 4; ++reg)
                C[(size_t)(r + reg) * NDIM + c] = acc[mi][nj][reg] + bv;
        }
    }
}

extern "C" void kernel_launch(void* const* d_in, const int* in_sizes, int n_in,
                              void* d_out, int out_size, void* d_ws, size_t ws_size,
                              hipStream_t stream) {
    const float* x    = (const float*)d_in[0];
    const float* w    = (const float*)d_in[1];
    const float* bias = (const float*)d_in[2];
    float* out = (float*)d_out;

    bf16_t* xq = (bf16_t*)d_ws;                         // 32 MB
    bf16_t* wq = xq + (size_t)NDIM * NDIM;              // 32 MB

    dim3 qgrid(1024, 2);
    quant_bfp<<<qgrid, 256, 0, stream>>>(x, xq, w, wq);

    dim3 grid(256);
    gemm_bfp<<<grid, 512, 0, stream>>>(xq, wq, bias, out);
}